// Round 1
// baseline (1937.968 us; speedup 1.0000x reference)
//
#include <hip/hip_runtime.h>
#include <cstdint>

#define N_ML 8      // MAX_LEN
#define GRU_TPB 512
#define GRU_NP 8    // paths per wave
#define GRU_PPB 64  // paths per block (8 waves * 8)

// dynamic LDS sizes (bytes)
#define GRU_SMEM ((12288 + 12288 + 192 + 192 + 8 * GRU_NP * 64 * 2) * 4)  // 132608
#define ECC_SMEM (32768 * 4)                                              // 131072

__device__ __forceinline__ float fsigmoid(float x) { return 1.f / (1.f + __expf(-x)); }
__device__ __forceinline__ float ftanh_(float x) {
    float e = __expf(-2.f * fabsf(x));
    float t = (1.f - e) / (1.f + e);
    return x >= 0.f ? t : -t;
}
__device__ __forceinline__ float fselu(float x) {
    const float sc = 1.0507009873554805f, al = 1.6732632423543772f;
    return x > 0.f ? sc * x : sc * al * (__expf(x) - 1.f);
}

// ---- prep: fold edge MLP (linear x linear) into one matrix ----
__global__ void prep_we_kernel(const float* __restrict__ ew1, const float* __restrict__ eb1,
                               const float* __restrict__ ew2, const float* __restrict__ eb2,
                               float* __restrict__ We, float* __restrict__ be) {
    int t = blockIdx.x * 256 + threadIdx.x;
    if (t < 4096) {
        int k = t >> 5, j = t & 31;
        float a = 0.f;
        for (int i = 0; i < 32; ++i) a = fmaf(ew1[k * 32 + i], ew2[i * 32 + j], a);
        We[t] = a;
    }
    if (blockIdx.x == 0 && threadIdx.x < 32) {
        int j = threadIdx.x;
        float a = eb2[j];
        for (int i = 0; i < 32; ++i) a = fmaf(eb1[i], ew2[i * 32 + j], a);
        be[j] = a;
    }
}

// ---- init states (buffers pre-zeroed by memset) ----
__global__ void init_states_kernel(const float* __restrict__ li, const float* __restrict__ ni,
                                   const float* __restrict__ pi, float* __restrict__ ls,
                                   float* __restrict__ ns, float* __restrict__ ps,
                                   int n_links, int n_nodes, int n_paths) {
    int t = blockIdx.x * 256 + threadIdx.x;
    if (t < n_links) ls[(size_t)t * 32] = li[t];
    if (t < n_nodes) ns[(size_t)t * 32] = ni[t];
    if (t < n_paths) {
        ps[(size_t)t * 64] = pi[t];
        ps[(size_t)t * 64 + 1] = pi[n_paths + t];
    }
}

// ---- inverse scatter index: idx[p][s] = e, lens[p] = count ----
__global__ void build_idx_kernel(const int* __restrict__ paths, const int* __restrict__ seqs,
                                 int* __restrict__ idx, int* __restrict__ lens, int E) {
    int e = blockIdx.x * 256 + threadIdx.x;
    if (e < E) {
        int p = paths[e], s = seqs[e];
        idx[(size_t)p * N_ML + s] = e;
        atomicAdd(&lens[p], 1);
    }
}

// ---- GRU scan over 8 steps, fused x-gather and m scatter-add ----
extern "C" __global__ void __launch_bounds__(GRU_TPB, 1)
gru_kernel(const float* __restrict__ ls, const float* __restrict__ ns,
           float* __restrict__ ps, float* __restrict__ m,
           const int* __restrict__ idx, const int* __restrict__ lens,
           const int* __restrict__ l2p, const int* __restrict__ n2p,
           const float* __restrict__ wx, const float* __restrict__ wh,
           const float* __restrict__ gb, int n_paths) {
    extern __shared__ float sm[];
    float* wx_l = sm;            // 64*192
    float* wh_l = sm + 12288;    // 64*192
    float* b0_l = sm + 24576;    // 192
    float* b1_l = sm + 24768;    // 192
    float* xhbase = sm + 24960;  // per-wave [NP][64] x then [NP][64] h

    int tid = threadIdx.x;
    {
        const float4* a = (const float4*)wx;
        const float4* b = (const float4*)wh;
        float4* la = (float4*)wx_l;
        float4* lb = (float4*)wh_l;
        for (int i = tid; i < 3072; i += GRU_TPB) { la[i] = a[i]; lb[i] = b[i]; }
        for (int i = tid; i < 192; i += GRU_TPB) { b0_l[i] = gb[i]; b1_l[i] = gb[192 + i]; }
    }
    __syncthreads();

    const int wv = tid >> 6, lane = tid & 63;
    float* x_l = xhbase + wv * (GRU_NP * 64 * 2);
    float* h_l = x_l + GRU_NP * 64;
    const int pbase = blockIdx.x * GRU_PPB + wv * GRU_NP;

    float hv[GRU_NP];
    int plen[GRU_NP];
#pragma unroll
    for (int p = 0; p < GRU_NP; ++p) {
        int pi = pbase + p;
        float h0 = 0.f;
        int ln = 0;
        if (pi < n_paths) { h0 = ps[(size_t)pi * 64 + lane]; ln = lens[pi]; }
        hv[p] = h0;
        plen[p] = ln;
        h_l[p * 64 + lane] = h0;
    }

    for (int t = 0; t < N_ML; ++t) {
        int ecur[GRU_NP];
#pragma unroll
        for (int p = 0; p < GRU_NP; ++p) {
            int pi = pbase + p;
            int e = (pi < n_paths) ? idx[(size_t)pi * N_ML + t] : -1;
            ecur[p] = e;
            float xv = 0.f;
            if (e >= 0) {
                xv = (lane < 32) ? ls[(size_t)l2p[e] * 32 + lane]
                                 : ns[(size_t)n2p[e] * 32 + (lane - 32)];
            }
            x_l[p * 64 + lane] = xv;
        }
        float az[GRU_NP], ar[GRU_NP], ah[GRU_NP];
        float bz[GRU_NP], br[GRU_NP], bh[GRU_NP];
#pragma unroll
        for (int p = 0; p < GRU_NP; ++p) {
            az[p] = b0_l[lane]; ar[p] = b0_l[64 + lane]; ah[p] = b0_l[128 + lane];
            bz[p] = b1_l[lane]; br[p] = b1_l[64 + lane]; bh[p] = b1_l[128 + lane];
        }
        for (int k4 = 0; k4 < 16; ++k4) {
            float wv6[6][4];
#pragma unroll
            for (int kk = 0; kk < 4; ++kk) {
                int k = k4 * 4 + kk;
                wv6[0][kk] = wx_l[k * 192 + lane];
                wv6[1][kk] = wx_l[k * 192 + 64 + lane];
                wv6[2][kk] = wx_l[k * 192 + 128 + lane];
                wv6[3][kk] = wh_l[k * 192 + lane];
                wv6[4][kk] = wh_l[k * 192 + 64 + lane];
                wv6[5][kk] = wh_l[k * 192 + 128 + lane];
            }
#pragma unroll
            for (int p = 0; p < GRU_NP; ++p) {
                float4 xq = *(const float4*)(x_l + p * 64 + k4 * 4);
                float4 hq = *(const float4*)(h_l + p * 64 + k4 * 4);
                az[p] = fmaf(xq.x, wv6[0][0], az[p]); ar[p] = fmaf(xq.x, wv6[1][0], ar[p]); ah[p] = fmaf(xq.x, wv6[2][0], ah[p]);
                bz[p] = fmaf(hq.x, wv6[3][0], bz[p]); br[p] = fmaf(hq.x, wv6[4][0], br[p]); bh[p] = fmaf(hq.x, wv6[5][0], bh[p]);
                az[p] = fmaf(xq.y, wv6[0][1], az[p]); ar[p] = fmaf(xq.y, wv6[1][1], ar[p]); ah[p] = fmaf(xq.y, wv6[2][1], ah[p]);
                bz[p] = fmaf(hq.y, wv6[3][1], bz[p]); br[p] = fmaf(hq.y, wv6[4][1], br[p]); bh[p] = fmaf(hq.y, wv6[5][1], bh[p]);
                az[p] = fmaf(xq.z, wv6[0][2], az[p]); ar[p] = fmaf(xq.z, wv6[1][2], ar[p]); ah[p] = fmaf(xq.z, wv6[2][2], ah[p]);
                bz[p] = fmaf(hq.z, wv6[3][2], bz[p]); br[p] = fmaf(hq.z, wv6[4][2], br[p]); bh[p] = fmaf(hq.z, wv6[5][2], bh[p]);
                az[p] = fmaf(xq.w, wv6[0][3], az[p]); ar[p] = fmaf(xq.w, wv6[1][3], ar[p]); ah[p] = fmaf(xq.w, wv6[2][3], ah[p]);
                bz[p] = fmaf(hq.w, wv6[3][3], bz[p]); br[p] = fmaf(hq.w, wv6[4][3], br[p]); bh[p] = fmaf(hq.w, wv6[5][3], bh[p]);
            }
        }
#pragma unroll
        for (int p = 0; p < GRU_NP; ++p) {
            float z = fsigmoid(az[p] + bz[p]);
            float r = fsigmoid(ar[p] + br[p]);
            float c = ftanh_(ah[p] + r * bh[p]);
            float hn = z * hv[p] + (1.f - z) * c;
            bool msk = (t < plen[p]);
            float nh = msk ? hn : hv[p];
            float ov = msk ? hn : 0.f;
            hv[p] = nh;
            h_l[p * 64 + lane] = nh;
            if (ecur[p] >= 0) atomicAdd(&m[(size_t)l2p[ecur[p]] * 64 + lane], ov);
        }
    }
#pragma unroll
    for (int p = 0; p < GRU_NP; ++p) {
        int pi = pbase + p;
        if (pi < n_paths) ps[(size_t)pi * 64 + lane] = hv[p];
    }
}

// ---- edge MLP (pre-folded): ls_new = con @ We + be ----
extern "C" __global__ void __launch_bounds__(256, 2)
edge_kernel(const float* __restrict__ ns, const float* __restrict__ lso,
            const float* __restrict__ m, const float* __restrict__ We,
            const float* __restrict__ be, const int* __restrict__ l2n,
            float* __restrict__ lsn, int n_links) {
    __shared__ float We_l[4096];
    __shared__ float be_l[32];
    __shared__ float con_l[8][128];
    int tid = threadIdx.x;
    for (int i = tid; i < 4096; i += 256) We_l[i] = We[i];
    if (tid < 32) be_l[tid] = be[tid];
    int li = tid >> 5, o = tid & 31;
    int l = blockIdx.x * 8 + li;
    if (l < n_links) {
        con_l[li][o] = ns[(size_t)l2n[l] * 32 + o];
        con_l[li][32 + o] = lso[(size_t)l * 32 + o];
        con_l[li][64 + o] = m[(size_t)l * 64 + o];
        con_l[li][96 + o] = m[(size_t)l * 64 + 32 + o];
    }
    __syncthreads();
    if (l >= n_links) return;
    float acc = be_l[o];
#pragma unroll 8
    for (int k = 0; k < 128; ++k) acc = fmaf(con_l[li][k], We_l[k * 32 + o], acc);
    lsn[(size_t)l * 32 + o] = acc;
}

// ---- ECCConv message: fused kernel-gen + matvec, agg via atomics ----
extern "C" __global__ void __launch_bounds__(256, 1)
ecc_kernel(const float* __restrict__ lsn, const float* __restrict__ ns,
           const float* __restrict__ wk, const float* __restrict__ bk,
           const int* __restrict__ senders, const int* __restrict__ receivers,
           float* __restrict__ agg, int n_links) {
    extern __shared__ float wk_l[];  // 32*1024 floats = 128 KB
    __shared__ float ls_s[8][32];
    __shared__ float ns_s[8][32];
    int tid = threadIdx.x;
    {
        const float4* a = (const float4*)wk;
        float4* la = (float4*)wk_l;
        for (int i = tid; i < 8192; i += 256) la[i] = a[i];
    }
    int li = tid >> 5, o = tid & 31;
    int l = blockIdx.x * 8 + li;
    if (l < n_links) {
        ls_s[li][o] = lsn[(size_t)l * 32 + o];
        ns_s[li][o] = ns[(size_t)senders[l] * 32 + o];
    }
    __syncthreads();
    if (l >= n_links) return;
    float acc = 0.f;
    for (int i = 0; i < 32; ++i) {
        float kio = bk[i * 32 + o];
#pragma unroll 8
        for (int j = 0; j < 32; ++j) kio = fmaf(ls_s[li][j], wk_l[j * 1024 + i * 32 + o], kio);
        acc = fmaf(ns_s[li][i], kio, acc);
    }
    atomicAdd(&agg[(size_t)receivers[l] * 32 + o], acc);
}

// ---- node update: ns_new = agg + ns_old @ wroot + broot ----
extern "C" __global__ void __launch_bounds__(256, 2)
node_kernel(const float* __restrict__ agg, const float* __restrict__ nso,
            const float* __restrict__ wroot, const float* __restrict__ broot,
            float* __restrict__ nsn, int n_nodes) {
    __shared__ float wr_l[1024];
    __shared__ float ns_s[8][32];
    int tid = threadIdx.x;
    for (int i = tid; i < 1024; i += 256) wr_l[i] = wroot[i];
    int ni = tid >> 5, o = tid & 31;
    int n = blockIdx.x * 8 + ni;
    if (n < n_nodes) ns_s[ni][o] = nso[(size_t)n * 32 + o];
    __syncthreads();
    if (n >= n_nodes) return;
    float acc = agg[(size_t)n * 32 + o] + broot[o];
#pragma unroll 8
    for (int k = 0; k < 32; ++k) acc = fmaf(ns_s[ni][k], wr_l[k * 32 + o], acc);
    nsn[(size_t)n * 32 + o] = acc;
}

// ---- readout: selu MLP + final head, 32 lanes per path ----
extern "C" __global__ void __launch_bounds__(256, 2)
readout_kernel(const float* __restrict__ ps, const float* __restrict__ w1,
               const float* __restrict__ b1, const float* __restrict__ w2,
               const float* __restrict__ b2, const float* __restrict__ fw,
               const float* __restrict__ fb, float* __restrict__ out, int n_paths) {
    __shared__ float w1_l[2048];
    __shared__ float w2_l[1024];
    __shared__ float fw_l[96];
    __shared__ float b1_l[32], b2_l[32];
    __shared__ float h_s[8][64];
    __shared__ float r1_s[8][32];
    int tid = threadIdx.x;
    for (int i = tid; i < 2048; i += 256) w1_l[i] = w1[i];
    for (int i = tid; i < 1024; i += 256) w2_l[i] = w2[i];
    if (tid < 96) fw_l[tid] = fw[tid];
    if (tid < 32) { b1_l[tid] = b1[tid]; b2_l[tid] = b2[tid]; }
    int li = tid >> 5, j = tid & 31;
    int p = blockIdx.x * 8 + li;
    bool ok = (p < n_paths);
    if (ok) {
        h_s[li][j] = ps[(size_t)p * 64 + j];
        h_s[li][32 + j] = ps[(size_t)p * 64 + 32 + j];
    }
    __syncthreads();
    float a = b1_l[j];
#pragma unroll 8
    for (int k = 0; k < 64; ++k) a = fmaf(h_s[li][k], w1_l[k * 32 + j], a);
    r1_s[li][j] = fselu(a);
    __syncthreads();
    float b = b2_l[j];
#pragma unroll 8
    for (int k = 0; k < 32; ++k) b = fmaf(r1_s[li][k], w2_l[k * 32 + j], b);
    float part = fselu(b) * fw_l[j] + h_s[li][j] * fw_l[32 + j] + h_s[li][32 + j] * fw_l[64 + j];
#pragma unroll
    for (int off = 16; off > 0; off >>= 1) part += __shfl_down(part, off, 32);
    if (j == 0 && ok) out[p] = part + fb[0];
}

extern "C" void kernel_launch(void* const* d_in, const int* in_sizes, int n_in,
                              void* d_out, int out_size, void* d_ws, size_t ws_size,
                              hipStream_t stream) {
    const float* link_init = (const float*)d_in[0];
    const float* node_init = (const float*)d_in[1];
    const float* path_init = (const float*)d_in[2];
    const float* gru_wx = (const float*)d_in[3];
    const float* gru_wh = (const float*)d_in[4];
    const float* gru_b = (const float*)d_in[5];
    const float* e_w1 = (const float*)d_in[6];
    const float* e_b1 = (const float*)d_in[7];
    const float* e_w2 = (const float*)d_in[8];
    const float* e_b2 = (const float*)d_in[9];
    const float* ecc_wk = (const float*)d_in[10];
    const float* ecc_bk = (const float*)d_in[11];
    const float* ecc_wroot = (const float*)d_in[12];
    const float* ecc_broot = (const float*)d_in[13];
    const float* r_w1 = (const float*)d_in[14];
    const float* r_b1 = (const float*)d_in[15];
    const float* r_w2 = (const float*)d_in[16];
    const float* r_b2 = (const float*)d_in[17];
    const float* f_w = (const float*)d_in[18];
    const float* f_b = (const float*)d_in[19];
    const int* p2l = (const int*)d_in[20];
    const int* sseq = (const int*)d_in[21];
    const int* l2p = (const int*)d_in[22];
    const int* n2p = (const int*)d_in[23];
    const int* l2n = (const int*)d_in[24];
    const int* senders = (const int*)d_in[25];
    const int* receivers = (const int*)d_in[26];

    const int nl = in_sizes[0];
    const int nn = in_sizes[1];
    const int np = in_sizes[2] / 2;
    const int E = in_sizes[20];

    char* base = (char*)d_ws;
    size_t off = 0;
    auto give = [&](size_t nbytes) -> void* {
        void* p = base + off;
        off += (nbytes + 255) & ~(size_t)255;
        return p;
    };
    float* ls0 = (float*)give((size_t)nl * 32 * 4);
    float* ls1 = (float*)give((size_t)nl * 32 * 4);
    float* ns0 = (float*)give((size_t)nn * 32 * 4);
    float* ns1 = (float*)give((size_t)nn * 32 * 4);
    float* ps = (float*)give((size_t)np * 64 * 4);
    float* m = (float*)give((size_t)nl * 64 * 4);
    float* agg = (float*)give((size_t)nn * 32 * 4);
    float* We = (float*)give(4096 * 4);
    float* be = (float*)give(32 * 4);
    int* idx = (int*)give((size_t)np * N_ML * 4);
    int* lensb = (int*)give((size_t)np * 4);
    float* lsb[2] = {ls0, ls1};
    float* nsb[2] = {ns0, ns1};

    // opt-in to >64KB dynamic LDS (ignore errors; ROCm typically allows up to 160KB)
    (void)hipFuncSetAttribute((const void*)gru_kernel, hipFuncAttributeMaxDynamicSharedMemorySize, GRU_SMEM);
    (void)hipFuncSetAttribute((const void*)ecc_kernel, hipFuncAttributeMaxDynamicSharedMemorySize, ECC_SMEM);

    hipMemsetAsync(ls0, 0, (size_t)nl * 32 * 4, stream);
    hipMemsetAsync(ns0, 0, (size_t)nn * 32 * 4, stream);
    hipMemsetAsync(ps, 0, (size_t)np * 64 * 4, stream);
    hipMemsetAsync(idx, 0xFF, (size_t)np * N_ML * 4, stream);
    hipMemsetAsync(lensb, 0, (size_t)np * 4, stream);

    prep_we_kernel<<<16, 256, 0, stream>>>(e_w1, e_b1, e_w2, e_b2, We, be);
    init_states_kernel<<<(np + 255) / 256, 256, 0, stream>>>(link_init, node_init, path_init,
                                                             ls0, ns0, ps, nl, nn, np);
    build_idx_kernel<<<(E + 255) / 256, 256, 0, stream>>>(p2l, sseq, idx, lensb, E);

    int cur = 0;
    for (int it = 0; it < 2; ++it) {
        hipMemsetAsync(m, 0, (size_t)nl * 64 * 4, stream);
        gru_kernel<<<(np + GRU_PPB - 1) / GRU_PPB, GRU_TPB, GRU_SMEM, stream>>>(
            lsb[cur], nsb[cur], ps, m, idx, lensb, l2p, n2p, gru_wx, gru_wh, gru_b, np);
        edge_kernel<<<(nl + 7) / 8, 256, 0, stream>>>(nsb[cur], lsb[cur], m, We, be, l2n,
                                                      lsb[1 - cur], nl);
        hipMemsetAsync(agg, 0, (size_t)nn * 32 * 4, stream);
        ecc_kernel<<<(nl + 7) / 8, 256, ECC_SMEM, stream>>>(lsb[1 - cur], nsb[cur], ecc_wk, ecc_bk,
                                                            senders, receivers, agg, nl);
        node_kernel<<<(nn + 7) / 8, 256, 0, stream>>>(agg, nsb[cur], ecc_wroot, ecc_broot,
                                                      nsb[1 - cur], nn);
        cur ^= 1;
    }
    readout_kernel<<<(np + 7) / 8, 256, 0, stream>>>(ps, r_w1, r_b1, r_w2, r_b2, f_w, f_b,
                                                     (float*)d_out, np);
}